// Round 1
// baseline (568.931 us; speedup 1.0000x reference)
//
#include <hip/hip_runtime.h>

// log2(1e-7): frac < 1e-7  <=>  log2(frac) < this
#define LOG2_EPS_CLAMP -23.2534966f

__device__ __forceinline__ float flog2(float x) { return __builtin_amdgcn_logf(x); }

__global__ __launch_bounds__(256) void pid_kernel(const float* __restrict__ p,
                                                  float* __restrict__ out,
                                                  const int N) {
    const int n = blockIdx.x * 256 + threadIdx.x;
    if (n >= N) return;
    const float* __restrict__ q = p + n;

    // marginals kept entirely in registers (only literal indexing below)
    float m0[16], m1[16], m02[32], m12[32];
    #pragma unroll
    for (int i = 0; i < 16; ++i) { m0[i] = 0.f; m1[i] = 0.f; }
    #pragma unroll
    for (int t = 0; t < 32; ++t) { m02[t] = 0.f; m12[t] = 0.f; }

    // ---- pass 1: marginals ----
    #pragma unroll
    for (int i = 0; i < 16; ++i) {
        #pragma unroll
        for (int j = 0; j < 16; ++j) {
            const int bin = (i * 16 + j) * 2;
            const float f0 = q[bin * N];
            const float f1 = q[bin * N + N];
            const float s = f0 + f1;
            m0[i] += s;
            m1[j] += s;
            m02[2 * i]     += f0;
            m02[2 * i + 1] += f1;
            m12[2 * j]     += f0;
            m12[2 * j + 1] += f1;
        }
    }

    float P20 = 0.f, P21 = 0.f;
    #pragma unroll
    for (int i = 0; i < 16; ++i) { P20 += m02[2 * i]; P21 += m02[2 * i + 1]; }
    const float LP20 = flog2(P20);
    const float LP21 = flog2(P21);

    // ---- pass 2: I_cap for antichains {0}{1} (I1) and {01} (I4) ----
    float I1 = 0.f, I4 = 0.f;
    #pragma unroll
    for (int i = 0; i < 16; ++i) {
        #pragma unroll
        for (int j = 0; j < 16; ++j) {
            const int bin = (i * 16 + j) * 2;
            const float f0 = q[bin * N];
            const float f1 = q[bin * N + N];
            const float p01 = f0 + f1;
            const float u1  = m0[i] + m1[j] - p01;   // union prob for {0}{1}
            const float Lu1  = flog2(u1);
            const float Lp01 = flog2(p01);
            // k = 0
            {
                const float num = m02[2 * i] + m12[2 * j] - f0;
                float l1 = flog2(num) - Lu1 - LP20;
                l1 = (l1 < LOG2_EPS_CLAMP) ? 0.f : l1;
                I1 = fmaf(f0, l1, I1);
                float l4 = flog2(f0) - Lp01 - LP20;
                l4 = (l4 < LOG2_EPS_CLAMP) ? 0.f : l4;
                I4 = fmaf(f0, l4, I4);
            }
            // k = 1
            {
                const float num = m02[2 * i + 1] + m12[2 * j + 1] - f1;
                float l1 = flog2(num) - Lu1 - LP21;
                l1 = (l1 < LOG2_EPS_CLAMP) ? 0.f : l1;
                I1 = fmaf(f1, l1, I1);
                float l4 = flog2(f1) - Lp01 - LP21;
                l4 = (l4 < LOG2_EPS_CLAMP) ? 0.f : l4;
                I4 = fmaf(f1, l4, I4);
            }
        }
    }

    // ---- I2 = I(X0;Y), I3 = I(X1;Y): collapsed to marginal sums ----
    float I2 = 0.f;
    #pragma unroll
    for (int i = 0; i < 16; ++i) {
        const float L0 = flog2(m0[i]);
        float la = flog2(m02[2 * i]) - L0 - LP20;
        la = (la < LOG2_EPS_CLAMP) ? 0.f : la;
        I2 = fmaf(m02[2 * i], la, I2);
        float lb = flog2(m02[2 * i + 1]) - L0 - LP21;
        lb = (lb < LOG2_EPS_CLAMP) ? 0.f : lb;
        I2 = fmaf(m02[2 * i + 1], lb, I2);
    }
    float I3 = 0.f;
    #pragma unroll
    for (int j = 0; j < 16; ++j) {
        const float L1 = flog2(m1[j]);
        float la = flog2(m12[2 * j]) - L1 - LP20;
        la = (la < LOG2_EPS_CLAMP) ? 0.f : la;
        I3 = fmaf(m12[2 * j], la, I3);
        float lb = flog2(m12[2 * j + 1]) - L1 - LP21;
        lb = (lb < LOG2_EPS_CLAMP) ? 0.f : lb;
        I3 = fmaf(m12[2 * j + 1], lb, I3);
    }

    const float H = -(P20 * flog2(P20 + 1e-10f) + P21 * flog2(P21 + 1e-10f));

    // outputs: red, unq0, unq1, syn, H_res  -> shape (5, N)
    out[0 * N + n] = I1;
    out[1 * N + n] = I2 - I1;
    out[2 * N + n] = I3 - I1;
    out[3 * N + n] = I1 - I2 - I3 + I4;
    out[4 * N + n] = H - I4;
}

extern "C" void kernel_launch(void* const* d_in, const int* in_sizes, int n_in,
                              void* d_out, int out_size, void* d_ws, size_t ws_size,
                              hipStream_t stream) {
    const float* p = (const float*)d_in[0];
    float* out = (float*)d_out;
    const int N = in_sizes[0] / 512;   // (16*16*2) bins per neuron
    const int blocks = (N + 255) / 256;
    pid_kernel<<<blocks, 256, 0, stream>>>(p, out, N);
}

// Round 2
// 335.896 us; speedup vs baseline: 1.6938x; 1.6938x over previous
//
#include <hip/hip_runtime.h>

// log2(1e-7): frac < 1e-7  <=>  log2(frac) < this
#define LOG2_EPS_CLAMP -23.2534966f

__device__ __forceinline__ float flog2(float x) { return __builtin_amdgcn_logf(x); }

__global__ __launch_bounds__(256) void pid_kernel(const float* __restrict__ p,
                                                  float* __restrict__ out,
                                                  const int N) {
    // m02 marginals live in LDS, one private column per thread.
    // addr = (idx*256 + tid)*4  -> bank = tid%32 -> 2 lanes/bank (free).
    __shared__ float lm02[32 * 256];
    const int tid = threadIdx.x;
    const int n = blockIdx.x * 256 + tid;
    if (n >= N) return;
    const float* __restrict__ q = p + n;
    float* __restrict__ c02 = &lm02[tid];

    // m12 marginals in registers: only compile-time indices (inner j unrolled).
    float m12[32];
    #pragma unroll
    for (int t = 0; t < 32; ++t) m12[t] = 0.f;

    // ---- pass 1: marginals ----
    #pragma unroll 1
    for (int i = 0; i < 16; ++i) {
        const float* __restrict__ qi = q + (size_t)(i * 32) * (size_t)N;
        float s0 = 0.f, s1 = 0.f;
        #pragma unroll
        for (int j = 0; j < 16; ++j) {
            const float f0 = qi[(size_t)(2 * j) * (size_t)N];
            const float f1 = qi[(size_t)(2 * j + 1) * (size_t)N];
            s0 += f0; s1 += f1;
            m12[2 * j]     += f0;
            m12[2 * j + 1] += f1;
        }
        c02[(2 * i) * 256]     = s0;
        c02[(2 * i + 1) * 256] = s1;
    }

    float P20 = 0.f, P21 = 0.f;
    #pragma unroll
    for (int j = 0; j < 16; ++j) { P20 += m12[2 * j]; P21 += m12[2 * j + 1]; }
    const float LP20 = flog2(P20);
    const float LP21 = flog2(P21);

    // ---- pass 2: I1 ({0}{1}), I4 ({01}), and I2 folded per-i ----
    float I1 = 0.f, I2 = 0.f, I4 = 0.f;
    #pragma unroll 1
    for (int i = 0; i < 16; ++i) {
        const float a0  = c02[(2 * i) * 256];
        const float a1  = c02[(2 * i + 1) * 256];
        const float m0i = a0 + a1;
        const float* __restrict__ qi = q + (size_t)(i * 32) * (size_t)N;
        #pragma unroll
        for (int j = 0; j < 16; ++j) {
            const float f0  = qi[(size_t)(2 * j) * (size_t)N];
            const float f1  = qi[(size_t)(2 * j + 1) * (size_t)N];
            const float p01 = f0 + f1;
            const float m1j = m12[2 * j] + m12[2 * j + 1];
            const float u1  = m0i + m1j - p01;     // union prob for {0}{1}
            const float Lu1  = flog2(u1);
            const float Lp01 = flog2(p01);
            // k = 0
            {
                const float num = a0 + m12[2 * j] - f0;
                float l1 = flog2(num) - Lu1 - LP20;
                l1 = (l1 < LOG2_EPS_CLAMP) ? 0.f : l1;
                I1 = fmaf(f0, l1, I1);
                float l4 = flog2(f0) - Lp01 - LP20;
                l4 = (l4 < LOG2_EPS_CLAMP) ? 0.f : l4;
                I4 = fmaf(f0, l4, I4);
            }
            // k = 1
            {
                const float num = a1 + m12[2 * j + 1] - f1;
                float l1 = flog2(num) - Lu1 - LP21;
                l1 = (l1 < LOG2_EPS_CLAMP) ? 0.f : l1;
                I1 = fmaf(f1, l1, I1);
                float l4 = flog2(f1) - Lp01 - LP21;
                l4 = (l4 < LOG2_EPS_CLAMP) ? 0.f : l4;
                I4 = fmaf(f1, l4, I4);
            }
        }
        // I2 contribution of this i (marginal over j)
        {
            const float L0 = flog2(m0i);
            float la = flog2(a0) - L0 - LP20;
            la = (la < LOG2_EPS_CLAMP) ? 0.f : la;
            I2 = fmaf(a0, la, I2);
            float lb = flog2(a1) - L0 - LP21;
            lb = (lb < LOG2_EPS_CLAMP) ? 0.f : lb;
            I2 = fmaf(a1, lb, I2);
        }
    }

    // ---- I3 = I(X1;Y) from m12 registers ----
    float I3 = 0.f;
    #pragma unroll
    for (int j = 0; j < 16; ++j) {
        const float L1 = flog2(m12[2 * j] + m12[2 * j + 1]);
        float la = flog2(m12[2 * j]) - L1 - LP20;
        la = (la < LOG2_EPS_CLAMP) ? 0.f : la;
        I3 = fmaf(m12[2 * j], la, I3);
        float lb = flog2(m12[2 * j + 1]) - L1 - LP21;
        lb = (lb < LOG2_EPS_CLAMP) ? 0.f : lb;
        I3 = fmaf(m12[2 * j + 1], lb, I3);
    }

    const float H = -(P20 * flog2(P20 + 1e-10f) + P21 * flog2(P21 + 1e-10f));

    // outputs: red, unq0, unq1, syn, H_res  -> shape (5, N)
    out[0 * N + n] = I1;
    out[1 * N + n] = I2 - I1;
    out[2 * N + n] = I3 - I1;
    out[3 * N + n] = I1 - I2 - I3 + I4;
    out[4 * N + n] = H - I4;
}

extern "C" void kernel_launch(void* const* d_in, const int* in_sizes, int n_in,
                              void* d_out, int out_size, void* d_ws, size_t ws_size,
                              hipStream_t stream) {
    const float* p = (const float*)d_in[0];
    float* out = (float*)d_out;
    const int N = in_sizes[0] / 512;   // (16*16*2) bins per neuron
    const int blocks = (N + 255) / 256;
    pid_kernel<<<blocks, 256, 0, stream>>>(p, out, N);
}

// Round 3
// 285.483 us; speedup vs baseline: 1.9929x; 1.1766x over previous
//
#include <hip/hip_runtime.h>

// log2(1e-7): frac < 1e-7  <=>  log2(frac) < this
#define LOG2_EPS_CLAMP -23.2534966f

__device__ __forceinline__ float flog2(float x) { return __builtin_amdgcn_logf(x); }

// 4 sub-threads per neuron: lane group {4g..4g+3}, sub s owns i in [4s, 4s+4).
__global__ __launch_bounds__(256) void pid_kernel(const float* __restrict__ p,
                                                  float* __restrict__ out,
                                                  const int N) {
    const int tid = threadIdx.x;
    const int g = tid >> 2;
    const int s = tid & 3;
    const int n = blockIdx.x * 64 + g;
    if (n >= N) return;               // whole 4-lane group exits together
    const float* __restrict__ q = p + n;

    // partial m12 (over own 4 i's) + own-i m02 slices, all registers
    float m12p[32];
    #pragma unroll
    for (int t = 0; t < 32; ++t) m12p[t] = 0.f;
    float a0[4], a1[4];

    // ---- phase 1: partial marginals ----
    #pragma unroll
    for (int ii = 0; ii < 4; ++ii) {
        const int i = s * 4 + ii;
        const float* __restrict__ qi = q + (size_t)(i * 32) * (size_t)N;
        float s0 = 0.f, s1 = 0.f;
        #pragma unroll
        for (int j = 0; j < 16; ++j) {
            const float f0 = qi[(size_t)(2 * j) * (size_t)N];
            const float f1 = qi[(size_t)(2 * j + 1) * (size_t)N];
            s0 += f0; s1 += f1;
            m12p[2 * j]     += f0;
            m12p[2 * j + 1] += f1;
        }
        a0[ii] = s0; a1[ii] = s1;
    }

    // butterfly-reduce m12 across the 4 sub-threads (DPP quad-perm)
    #pragma unroll
    for (int t = 0; t < 32; ++t) {
        m12p[t] += __shfl_xor(m12p[t], 1, 64);
        m12p[t] += __shfl_xor(m12p[t], 2, 64);
    }

    float P20 = 0.f, P21 = 0.f;
    #pragma unroll
    for (int j = 0; j < 16; ++j) { P20 += m12p[2 * j]; P21 += m12p[2 * j + 1]; }
    const float LP20 = flog2(P20);
    const float LP21 = flog2(P21);

    // ---- phase 2: I1 ({0}{1}), I4 ({01}), I2 folded per own i ----
    float I1 = 0.f, I2 = 0.f, I4 = 0.f;
    #pragma unroll
    for (int ii = 0; ii < 4; ++ii) {
        const int i = s * 4 + ii;
        const float a0i = a0[ii], a1i = a1[ii];
        const float m0i = a0i + a1i;
        const float* __restrict__ qi = q + (size_t)(i * 32) * (size_t)N;
        #pragma unroll
        for (int j = 0; j < 16; ++j) {
            const float f0  = qi[(size_t)(2 * j) * (size_t)N];
            const float f1  = qi[(size_t)(2 * j + 1) * (size_t)N];
            const float p01 = f0 + f1;
            const float m1j = m12p[2 * j] + m12p[2 * j + 1];
            const float u1  = m0i + m1j - p01;
            const float Lu1  = flog2(u1);
            const float Lp01 = flog2(p01);
            // k = 0
            {
                const float num = a0i + m12p[2 * j] - f0;
                float l1 = flog2(num) - Lu1 - LP20;
                l1 = (l1 < LOG2_EPS_CLAMP) ? 0.f : l1;
                I1 = fmaf(f0, l1, I1);
                float l4 = flog2(f0) - Lp01 - LP20;
                l4 = (l4 < LOG2_EPS_CLAMP) ? 0.f : l4;
                I4 = fmaf(f0, l4, I4);
            }
            // k = 1
            {
                const float num = a1i + m12p[2 * j + 1] - f1;
                float l1 = flog2(num) - Lu1 - LP21;
                l1 = (l1 < LOG2_EPS_CLAMP) ? 0.f : l1;
                I1 = fmaf(f1, l1, I1);
                float l4 = flog2(f1) - Lp01 - LP21;
                l4 = (l4 < LOG2_EPS_CLAMP) ? 0.f : l4;
                I4 = fmaf(f1, l4, I4);
            }
        }
        // I2 contribution of this i
        const float L0 = flog2(m0i);
        float la = flog2(a0i) - L0 - LP20;
        la = (la < LOG2_EPS_CLAMP) ? 0.f : la;
        I2 = fmaf(a0i, la, I2);
        float lb = flog2(a1i) - L0 - LP21;
        lb = (lb < LOG2_EPS_CLAMP) ? 0.f : lb;
        I2 = fmaf(a1i, lb, I2);
    }

    // reduce I1, I2, I4 across the 4 sub-threads
    I1 += __shfl_xor(I1, 1, 64); I1 += __shfl_xor(I1, 2, 64);
    I2 += __shfl_xor(I2, 1, 64); I2 += __shfl_xor(I2, 2, 64);
    I4 += __shfl_xor(I4, 1, 64); I4 += __shfl_xor(I4, 2, 64);

    // ---- I3 = I(X1;Y): uniform within the group (full m12) ----
    float I3 = 0.f;
    #pragma unroll
    for (int j = 0; j < 16; ++j) {
        const float L1 = flog2(m12p[2 * j] + m12p[2 * j + 1]);
        float la = flog2(m12p[2 * j]) - L1 - LP20;
        la = (la < LOG2_EPS_CLAMP) ? 0.f : la;
        I3 = fmaf(m12p[2 * j], la, I3);
        float lb = flog2(m12p[2 * j + 1]) - L1 - LP21;
        lb = (lb < LOG2_EPS_CLAMP) ? 0.f : lb;
        I3 = fmaf(m12p[2 * j + 1], lb, I3);
    }

    const float H = -(P20 * flog2(P20 + 1e-10f) + P21 * flog2(P21 + 1e-10f));

    if (s == 0) {
        out[0 * N + n] = I1;
        out[1 * N + n] = I2 - I1;
        out[2 * N + n] = I3 - I1;
        out[3 * N + n] = I1 - I2 - I3 + I4;
        out[4 * N + n] = H - I4;
    }
}

extern "C" void kernel_launch(void* const* d_in, const int* in_sizes, int n_in,
                              void* d_out, int out_size, void* d_ws, size_t ws_size,
                              hipStream_t stream) {
    const float* p = (const float*)d_in[0];
    float* out = (float*)d_out;
    const int N = in_sizes[0] / 512;          // (16*16*2) bins per neuron
    const int blocks = (N + 63) / 64;         // 4 threads per neuron, 256/block
    pid_kernel<<<blocks, 256, 0, stream>>>(p, out, N);
}